// Round 6
// baseline (76.547 us; speedup 1.0000x reference)
//
#include <hip/hip_runtime.h>
#include <hip/hip_bf16.h>

#define NROWS 8192
#define DIM 64
#define NT 64                     // 64x64 grid of 128x128 tiles
#define NTRI (NT * (NT + 1) / 2)  // 2080 upper-triangle tiles
#define GRID 512                  // persistent blocks, ~4 tiles each

typedef __attribute__((ext_vector_type(8))) short short8;   // 8 bf16 = 4 VGPRs
typedef __attribute__((ext_vector_type(4))) float f32x4;    // MFMA 16x16 accumulator

static constexpr float LOG2E = 1.4426950408889634f;

#if defined(__has_builtin) && __has_builtin(__builtin_amdgcn_exp2f)
#define EXP2F(x) __builtin_amdgcn_exp2f(x)
#else
#define EXP2F(x) exp2f(x)
#endif

// Prep: Xs = bf16(X*sqrt(params)) in panelized MFMA-fragment order, and
// Lt[row] = (log2e*||Xs_row||^2, t[row]) packed as float2.
// Panel layout: 16B unit index = p*128 + (k/8)*16 + (row%16), so an MFMA A/B
// fragment load is one fully-coalesced contiguous 1KB wave load.
__global__ __launch_bounds__(256) void prep_kernel(const float* __restrict__ X,
                                                   const float* __restrict__ params,
                                                   const float* __restrict__ t,
                                                   float2* __restrict__ Lt,
                                                   short* __restrict__ Xp) {
    int tid  = threadIdx.x;
    int wave = tid >> 6, lane = tid & 63;
    int r8 = lane >> 3, c = lane & 7;        // 8 rows x 8 k-chunks per wave
    int row = blockIdx.x * 32 + wave * 8 + r8;

    const float* xr = X + row * DIM + c * 8;
    float4 x0 = *(const float4*)xr;
    float4 x1 = *(const float4*)(xr + 4);
    float4 p0 = *(const float4*)(params + c * 8);
    float4 p1 = *(const float4*)(params + c * 8 + 4);

    float v[8];
    v[0] = x0.x * sqrtf(p0.x); v[1] = x0.y * sqrtf(p0.y);
    v[2] = x0.z * sqrtf(p0.z); v[3] = x0.w * sqrtf(p0.w);
    v[4] = x1.x * sqrtf(p1.x); v[5] = x1.y * sqrtf(p1.y);
    v[6] = x1.z * sqrtf(p1.z); v[7] = x1.w * sqrtf(p1.w);

    short8 h;
    float s = 0.f;
    #pragma unroll
    for (int i = 0; i < 8; ++i) {
        __hip_bfloat16 b = __float2bfloat16(v[i]);
        union { __hip_bfloat16 bb; short ss; } u; u.bb = b;
        h[i] = u.ss;
        float bf = __bfloat162float(b);   // rounded value == what MFMA multiplies
        s += bf * bf;
    }
    int panel = row >> 4, pr = row & 15;
    ((short8*)Xp)[panel * 128 + c * 16 + pr] = h;

    #pragma unroll
    for (int m = 1; m < 8; m <<= 1) s += __shfl_xor(s, m, 64);
    if (c == 0) Lt[row] = make_float2(LOG2E * s, t[row]);
}

// Main: persistent blocks (512), grid-stride over 2080 upper-triangle 128x128
// tiles; 4 waves/block, each computing a 64x64 subtile via 16x16x32 bf16 MFMA.
// Cross-tile software pipeline: after MFMA(t) issues (frag regs dead), issue
// tile t+1's 16 fragment loads, THEN run the exp epilogue of tile t from the
// accumulators — the ~950-cycle epilogue hides the next tile's L2 latency.
// s1/s2 accumulate across all the block's tiles; one LDS reduce + one store
// per block.
// No diagonal special-case: Lsq is built from the SAME rounded-bf16 products
// the MFMA accumulates -> K_diag = 1 +- ~1e-5 (validated absmax 0.0 in R2-R5);
// off-diag d2 >= ~15 so the max(d2,0) clamp never binds.
__global__ __launch_bounds__(256, 3) void kta_main(const short* __restrict__ Xp,
                                                   const float2* __restrict__ Lt,
                                                   float2* __restrict__ partial) {
    int tid  = threadIdx.x;
    int wave = tid >> 6, lane = tid & 63;
    int quad = lane >> 4, l16 = lane & 15;
    int rsub = (wave >> 1) * 64, csub = (wave & 1) * 64;

    const short8* Xpv = (const short8*)Xp;

    auto decode = [](int k, int& it, int& jt) {
        int i = (int)((129.0f - sqrtf(16641.0f - 8.0f * (float)k)) * 0.5f);
        if (i > NT - 1) i = NT - 1;
        while ((i * (129 - i)) / 2 > k) --i;
        while (((i + 1) * (128 - i)) / 2 <= k) ++i;
        it = i; jt = i + (k - (i * (129 - i)) / 2);
    };

    short8 afr[4][2], bfr[4][2];
    float2 ltc[4];
    auto load_tile = [&](int rbase, int cbase) {
        int pA0 = rbase >> 4, pB0 = cbase >> 4;
        #pragma unroll
        for (int rt = 0; rt < 4; ++rt) {
            #pragma unroll
            for (int kc = 0; kc < 2; ++kc) {
                afr[rt][kc] = Xpv[(pA0 + rt) * 128 + (kc * 4 + quad) * 16 + l16];
                bfr[rt][kc] = Xpv[(pB0 + rt) * 128 + (kc * 4 + quad) * 16 + l16];
            }
        }
        #pragma unroll
        for (int ct = 0; ct < 4; ++ct)
            ltc[ct] = Lt[cbase + ct * 16 + l16];
    };

    float s1 = 0.f, s2 = 0.f;
    int k = blockIdx.x;
    int it, jt;
    decode(k, it, jt);
    int rbase = it * 128 + rsub, cbase = jt * 128 + csub;
    float w = (it == jt) ? 1.0f : 2.0f;
    load_tile(rbase, cbase);

    while (true) {
        int rb = rbase;
        float wcur = w;

        // MFMA: 32 ops, acc c[4][4]. C/D layout: col = lane&15, row = quad*4+reg.
        f32x4 c[4][4];
        #pragma unroll
        for (int rt = 0; rt < 4; ++rt)
            #pragma unroll
            for (int ct = 0; ct < 4; ++ct)
                c[rt][ct] = __builtin_amdgcn_mfma_f32_16x16x32_bf16(
                    afr[rt][0], bfr[ct][0], (f32x4){0.f, 0.f, 0.f, 0.f}, 0, 0, 0);
        #pragma unroll
        for (int rt = 0; rt < 4; ++rt)
            #pragma unroll
            for (int ct = 0; ct < 4; ++ct)
                c[rt][ct] = __builtin_amdgcn_mfma_f32_16x16x32_bf16(
                    afr[rt][1], bfr[ct][1], c[rt][ct], 0, 0, 0);

        // Save current tile's column scalars before next-tile loads overwrite ltc.
        float negLC[4], tC[4];
        #pragma unroll
        for (int ct = 0; ct < 4; ++ct) {
            negLC[ct] = -ltc[ct].x;
            tC[ct]    = ltc[ct].y;
        }

        // Prefetch next tile's fragments (frag regs are dead after MFMA issue).
        int kn = k + GRID;
        bool more = (kn < NTRI);
        if (more) {
            decode(kn, it, jt);
            rbase = it * 128 + rsub;
            cbase = jt * 128 + csub;
            w = (it == jt) ? 1.0f : 2.0f;
            load_tile(rbase, cbase);
        }

        // Epilogue of current tile — hides the prefetch latency.
        float ts1 = 0.f, ts2 = 0.f;
        #pragma unroll
        for (int rt = 0; rt < 4; ++rt) {
            float2 LtR[4];
            #pragma unroll
            for (int r = 0; r < 4; ++r)
                LtR[r] = Lt[rb + rt * 16 + quad * 4 + r];
            #pragma unroll
            for (int r = 0; r < 4; ++r) {
                float nr = LtR[r].x;
                float s1row = 0.f;
                #pragma unroll
                for (int ct = 0; ct < 4; ++ct) {
                    float K = EXP2F(fmaf(c[rt][ct][r], 2.0f * LOG2E, negLC[ct] - nr));
                    s1row = fmaf(K, tC[ct], s1row);
                    ts2   = fmaf(K, K, ts2);
                }
                ts1 = fmaf(s1row, LtR[r].y, ts1);
            }
        }
        s1 = fmaf(ts1, wcur, s1);
        s2 = fmaf(ts2, wcur, s2);

        if (!more) break;
        k = kn;
    }

    #pragma unroll
    for (int m = 32; m > 0; m >>= 1) {
        s1 += __shfl_xor(s1, m, 64);
        s2 += __shfl_xor(s2, m, 64);
    }
    __shared__ float2 red[4];
    if (lane == 0) red[wave] = make_float2(s1, s2);
    __syncthreads();
    if (tid == 0) {
        float2 a = red[0], b = red[1], cc = red[2], d = red[3];
        partial[blockIdx.x] = make_float2(a.x + b.x + cc.x + d.x, a.y + b.y + cc.y + d.y);
    }
}

// Single-block reduction of per-block partials (512 float2 = 4 KB).
__global__ __launch_bounds__(256) void finalize_kernel(const float2* __restrict__ partial,
                                                       float* __restrict__ out) {
    float s1 = 0.f, s2 = 0.f;
    for (int i = threadIdx.x; i < GRID; i += 256) {
        float2 p = partial[i];
        s1 += p.x;
        s2 += p.y;
    }
    #pragma unroll
    for (int m = 32; m > 0; m >>= 1) {
        s1 += __shfl_xor(s1, m, 64);
        s2 += __shfl_xor(s2, m, 64);
    }
    __shared__ float r1[4], r2[4];
    int wave = threadIdx.x >> 6, lane = threadIdx.x & 63;
    if (lane == 0) { r1[wave] = s1; r2[wave] = s2; }
    __syncthreads();
    if (threadIdx.x == 0) {
        float a = r1[0] + r1[1] + r1[2] + r1[3];
        float b = r2[0] + r2[1] + r2[2] + r2[3];
        out[0] = -a / ((float)NROWS * sqrtf(b));
    }
}

extern "C" void kernel_launch(void* const* d_in, const int* in_sizes, int n_in,
                              void* d_out, int out_size, void* d_ws, size_t ws_size,
                              hipStream_t stream) {
    const float* X      = (const float*)d_in[0];
    const float* target = (const float*)d_in[1];
    const float* params = (const float*)d_in[2];
    float* out = (float*)d_out;

    float* ws = (float*)d_ws;
    float2* partial = (float2*)ws;                    // 512 float2 (4 KB)
    float2* Lt = (float2*)(ws + 8192);                // 8192 float2 (64 KB)
    short*  Xp = (short*)(ws + 8192 + 16384);         // panelized bf16 (1 MB)

    prep_kernel<<<NROWS / 32, 256, 0, stream>>>(X, params, target, Lt, Xp);
    kta_main<<<GRID, 256, 0, stream>>>(Xp, Lt, partial);
    finalize_kernel<<<1, 256, 0, stream>>>(partial, out);
}

// Round 7
// 74.484 us; speedup vs baseline: 1.0277x; 1.0277x over previous
//
#include <hip/hip_runtime.h>
#include <hip/hip_bf16.h>

#define NROWS 8192
#define DIM 64
#define NT 64                  // 64x64 grid of 128x128 tiles
#define NTRI (NT * (NT + 1) / 2)  // 2080 upper-triangle tiles

typedef __attribute__((ext_vector_type(8))) short short8;   // 8 bf16 = 4 VGPRs
typedef __attribute__((ext_vector_type(4))) float f32x4;    // MFMA 16x16 accumulator

static constexpr float LOG2E = 1.4426950408889634f;

#if defined(__has_builtin) && __has_builtin(__builtin_amdgcn_exp2f)
#define EXP2F(x) __builtin_amdgcn_exp2f(x)
#else
#define EXP2F(x) exp2f(x)
#endif

// Best-measured configuration (R3, 74.2 us). Subsequent experiments:
//  - launch_bounds(256,4) + kc-split regs (R5): 74.9 (noise-neutral)
//  - persistent blocks + cross-tile prefetch (R6): 76.5 (regressed)
//  - cooperative fusion w/ grid.sync (R4): 174.2 (grid.sync ~dozens of us; never again)
// Total is dominated by ~64 us of harness-fixed overhead (256 MB d_ws re-poison
// fill ~41 us + restore/memset/gaps); the three kernels sum to ~10 us.
//
// Panelized bf16 layout: panel p = row/16 holds rows 16p..16p+15.
// Within a panel, 8 k-chunks (c = k/8), stored chunk-major in 16B units:
//   unit_index = p*128 + c*16 + (row%16)
// An MFMA A/B fragment load (lane l16 = row%16, quad = (k/8)%4) is then a
// fully-coalesced contiguous 1KB wave load — no cache-line splits.
__global__ __launch_bounds__(256) void prep_kernel(const float* __restrict__ X,
                                                   const float* __restrict__ params,
                                                   float* __restrict__ Lsq,
                                                   short* __restrict__ Xp) {
    int tid  = threadIdx.x;
    int wave = tid >> 6, lane = tid & 63;
    int r8 = lane >> 3, c = lane & 7;        // 8 rows x 8 chunks per wave
    int row = blockIdx.x * 32 + wave * 8 + r8;

    const float* xr = X + row * DIM + c * 8;
    float4 x0 = *(const float4*)xr;
    float4 x1 = *(const float4*)(xr + 4);
    float4 p0 = *(const float4*)(params + c * 8);
    float4 p1 = *(const float4*)(params + c * 8 + 4);

    float v[8];
    v[0] = x0.x * sqrtf(p0.x); v[1] = x0.y * sqrtf(p0.y);
    v[2] = x0.z * sqrtf(p0.z); v[3] = x0.w * sqrtf(p0.w);
    v[4] = x1.x * sqrtf(p1.x); v[5] = x1.y * sqrtf(p1.y);
    v[6] = x1.z * sqrtf(p1.z); v[7] = x1.w * sqrtf(p1.w);

    short8 h;
    float s = 0.f;
    #pragma unroll
    for (int i = 0; i < 8; ++i) {
        __hip_bfloat16 b = __float2bfloat16(v[i]);
        union { __hip_bfloat16 bb; short ss; } u; u.bb = b;
        h[i] = u.ss;
        float bf = __bfloat162float(b);   // rounded value, consistent with MFMA dot
        s += bf * bf;
    }

    int panel = row >> 4, pr = row & 15;
    ((short8*)Xp)[panel * 128 + c * 16 + pr] = h;

    // sum s over the 8 chunk-lanes of this row (xor over lane bits 0..2)
    #pragma unroll
    for (int m = 1; m < 8; m <<= 1) s += __shfl_xor(s, m, 64);
    if (c == 0) Lsq[row] = LOG2E * s;
}

// Main: compact upper-triangle grid of 128x128 tiles; each of 4 waves computes
// a 64x64 subtile via 16x16x32 bf16 MFMA from the panelized layout, then a
// fused exp epilogue. Per-block LDS reduce -> one float2 per block.
// No diagonal special-case: Lsq is built from the SAME rounded-bf16 products
// the MFMA accumulates -> K_diag = 1 +- ~1e-5 (validated absmax 0.0 R2-R6);
// off-diag d2 >= ~15 for this data so the max(d2,0) clamp never binds.
__global__ __launch_bounds__(256) void kta_main(const short* __restrict__ Xp,
                                                const float* __restrict__ Lsq,
                                                const float* __restrict__ t,
                                                float2* __restrict__ partial) {
    int k = blockIdx.x;
    // decode triangular index: row it has tiles jt = it..NT-1; C(i)=i*(129-i)/2
    int it = (int)((129.0f - sqrtf(16641.0f - 8.0f * (float)k)) * 0.5f);
    if (it > NT - 1) it = NT - 1;
    while ((it * (129 - it)) / 2 > k) --it;
    while (((it + 1) * (128 - it)) / 2 <= k) ++it;
    int jt = it + (k - (it * (129 - it)) / 2);

    int tid  = threadIdx.x;
    int wave = tid >> 6, lane = tid & 63;
    int quad = lane >> 4, l16 = lane & 15;
    int rbase = it * 128 + (wave >> 1) * 64;
    int cbase = jt * 128 + (wave & 1) * 64;

    // Coalesced fragment loads from panelized Xs.
    // A-operand (16x16x32 bf16): lane holds A[m=l16][k=quad*8+j]; B symmetric.
    const short8* Xpv = (const short8*)Xp;
    int pA0 = rbase >> 4, pB0 = cbase >> 4;
    short8 afr[4][2], bfr[4][2];
    #pragma unroll
    for (int rt = 0; rt < 4; ++rt) {
        #pragma unroll
        for (int kc = 0; kc < 2; ++kc) {
            afr[rt][kc] = Xpv[(pA0 + rt) * 128 + (kc * 4 + quad) * 16 + l16];
            bfr[rt][kc] = Xpv[(pB0 + rt) * 128 + (kc * 4 + quad) * 16 + l16];
        }
    }

    f32x4 c[4][4];
    #pragma unroll
    for (int rt = 0; rt < 4; ++rt)
        #pragma unroll
        for (int ct = 0; ct < 4; ++ct)
            c[rt][ct] = (f32x4){0.f, 0.f, 0.f, 0.f};

    #pragma unroll
    for (int rt = 0; rt < 4; ++rt)
        #pragma unroll
        for (int ct = 0; ct < 4; ++ct) {
            c[rt][ct] = __builtin_amdgcn_mfma_f32_16x16x32_bf16(afr[rt][0], bfr[ct][0], c[rt][ct], 0, 0, 0);
            c[rt][ct] = __builtin_amdgcn_mfma_f32_16x16x32_bf16(afr[rt][1], bfr[ct][1], c[rt][ct], 0, 0, 0);
        }

    // Epilogue. C/D layout: col = lane&15, row = quad*4 + reg.
    float LsqR[4][4], tR[4][4];
    #pragma unroll
    for (int rt = 0; rt < 4; ++rt)
        #pragma unroll
        for (int r = 0; r < 4; ++r) {
            int row = rbase + rt * 16 + quad * 4 + r;
            LsqR[rt][r] = Lsq[row];
            tR[rt][r]   = t[row];
        }
    float LsqC[4], tC[4];
    #pragma unroll
    for (int ct = 0; ct < 4; ++ct) {
        int col = cbase + ct * 16 + l16;
        LsqC[ct] = Lsq[col];
        tC[ct]   = t[col];
    }

    float s1 = 0.f, s2 = 0.f;
    #pragma unroll
    for (int rt = 0; rt < 4; ++rt)
        #pragma unroll
        for (int r = 0; r < 4; ++r) {
            float nr = LsqR[rt][r];
            float s1row = 0.f;
            #pragma unroll
            for (int ct = 0; ct < 4; ++ct) {
                float K = EXP2F(fmaf(c[rt][ct][r], 2.0f * LOG2E, -(nr + LsqC[ct])));
                s1row = fmaf(K, tC[ct], s1row);
                s2    = fmaf(K, K, s2);
            }
            s1 = fmaf(s1row, tR[rt][r], s1);
        }

    float w = (it == jt) ? 1.0f : 2.0f;
    s1 *= w; s2 *= w;
    #pragma unroll
    for (int m = 32; m > 0; m >>= 1) {
        s1 += __shfl_xor(s1, m, 64);
        s2 += __shfl_xor(s2, m, 64);
    }

    __shared__ float2 red[4];
    if (lane == 0) red[wave] = make_float2(s1, s2);
    __syncthreads();
    if (tid == 0) {
        float2 a = red[0], b = red[1], cc = red[2], d = red[3];
        partial[k] = make_float2(a.x + b.x + cc.x + d.x, a.y + b.y + cc.y + d.y);
    }
}

// Single-block reduction of per-block partials (2080 float2 = 16.6 KB).
__global__ __launch_bounds__(256) void finalize_kernel(const float2* __restrict__ partial,
                                                       float* __restrict__ out) {
    float s1 = 0.f, s2 = 0.f;
    for (int i = threadIdx.x; i < NTRI; i += 256) {
        float2 p = partial[i];
        s1 += p.x;
        s2 += p.y;
    }
    #pragma unroll
    for (int m = 32; m > 0; m >>= 1) {
        s1 += __shfl_xor(s1, m, 64);
        s2 += __shfl_xor(s2, m, 64);
    }
    __shared__ float r1[4], r2[4];
    int wave = threadIdx.x >> 6, lane = threadIdx.x & 63;
    if (lane == 0) { r1[wave] = s1; r2[wave] = s2; }
    __syncthreads();
    if (threadIdx.x == 0) {
        float a = r1[0] + r1[1] + r1[2] + r1[3];
        float b = r2[0] + r2[1] + r2[2] + r2[3];
        out[0] = -a / ((float)NROWS * sqrtf(b));
    }
}

extern "C" void kernel_launch(void* const* d_in, const int* in_sizes, int n_in,
                              void* d_out, int out_size, void* d_ws, size_t ws_size,
                              hipStream_t stream) {
    const float* X      = (const float*)d_in[0];
    const float* target = (const float*)d_in[1];
    const float* params = (const float*)d_in[2];
    float* out = (float*)d_out;

    float* ws = (float*)d_ws;
    float2* partial = (float2*)ws;                 // 2080 float2 (16.6 KB)
    float* Lsq = ws + 8192;                        // 8192 floats (32 KB)
    short* Xp  = (short*)(ws + 16384);             // panelized bf16, 1 MB

    prep_kernel<<<NROWS / 32, 256, 0, stream>>>(X, params, Lsq, Xp);
    kta_main<<<NTRI, 256, 0, stream>>>(Xp, Lsq, target, partial);
    finalize_kernel<<<1, 256, 0, stream>>>(partial, out);
}